// Round 3
// baseline (374.303 us; speedup 1.0000x reference)
//
#include <hip/hip_runtime.h>

// ISDLoss_only_type1: masked symmetric KL between mixed conf and interpolation.
// B=128, N=8732, C=21; fp32 in, scalar fp32 out.
//
// R3: 4 rows per thread. 4 rows = 84 floats = 21 exactly-aligned float4s
// (336 B per group, %16==0), so each row needs just 6 float4 loads/tensor
// (vs 21 scalar). N%4==0 -> groups never straddle batches, so the
// conf_shuffle batch-half swap stays float4-exact. All unpack indices are
// static after unroll -> pure register selects. No LDS tiles, no barriers
// in the hot path (R2's stage/barrier structure serialized the pipeline).

#define EPS 1e-7f

constexpr int B = 128;
constexpr int N = 8732;
constexpr int C = 21;
constexpr int ROWS = B * N;               // 1,117,696
constexpr int GROUPS = ROWS / 4;          // 279,424 threads, 4 rows each
constexpr int BLOCK = 256;
constexpr int GRID = (GROUPS + BLOCK - 1) / BLOCK;   // 1092
constexpr int NB4 = N / 4;                // 2183 row-groups per batch
constexpr int BATCH_F4 = (N * C) / 4;     // 45843 float4s per batch

__global__ __launch_bounds__(BLOCK) void isd_main_kernel(
    const float* __restrict__ lam_p,
    const float* __restrict__ conf,
    const float* __restrict__ csh,   // conf_shuffle
    const float* __restrict__ cin,   // conf_interpolation
    double* __restrict__ partials)   // [2*GRID]: (sum, cnt) per block
{
    const float lam = lam_p[0];
    const float oml = 1.0f - lam;

    const float4* conf4 = (const float4*)conf;
    const float4* csh4  = (const float4*)csh;
    const float4* cin4  = (const float4*)cin;

    const int t = blockIdx.x * BLOCK + threadIdx.x;

    float sum = 0.0f;
    float cnt = 0.0f;

    if (t < GROUPS) {
        const int b  = t / NB4;
        const int g  = t - b * NB4;                    // row-group within batch
        const size_t f4c = (size_t)t * 21;             // conf / cin float4 base
        const size_t f4s = (size_t)(b ^ 64) * BATCH_F4 + (size_t)g * 21;  // swapped csh base

        #pragma unroll
        for (int j = 0; j < 4; ++j) {
            const int fs = (21 * j) >> 2;              // 0,5,10,15
            // phase p == j: row floats live at window offsets [j, j+20]

            float4 ax[6], sx[6], ix[6];
            #pragma unroll
            for (int q = 0; q < 6; ++q) {
                ax[q] = conf4[f4c + fs + q];
                sx[q] = csh4 [f4s + fs + q];
                ix[q] = cin4 [f4c + fs + q];
            }

            float av[24], sv[24], iv_[24];
            #pragma unroll
            for (int q = 0; q < 6; ++q) {
                av[4*q+0] = ax[q].x; av[4*q+1] = ax[q].y; av[4*q+2] = ax[q].z; av[4*q+3] = ax[q].w;
                sv[4*q+0] = sx[q].x; sv[4*q+1] = sx[q].y; sv[4*q+2] = sx[q].z; sv[4*q+3] = sx[q].w;
                iv_[4*q+0] = ix[q].x; iv_[4*q+1] = ix[q].y; iv_[4*q+2] = ix[q].z; iv_[4*q+3] = ix[q].w;
            }

            float c0 = 0.0f, t0 = 0.0f;
            float cmax = -1e30f, tmax = -1e30f;
            float kl = 0.0f;

            #pragma unroll
            for (int c = 0; c < C; ++c) {
                const float cv = av[j + c];
                const float tv = sv[j + c];
                const float iv = iv_[j + c] + EPS;
                const float mv = fmaf(lam, cv, oml * tv) + EPS;
                // kl_a + kl_b per class: iv*(li-lm) + mv*(lm-li) == (iv-mv)*(li-lm)
                kl += (iv - mv) * (__logf(iv) - __logf(mv));
                if (c == 0) { c0 = cv; t0 = tv; }
                else        { cmax = fmaxf(cmax, cv); tmax = fmaxf(tmax, tv); }
            }

            const float msk = ((cmax > c0) && (tmax > t0)) ? 1.0f : 0.0f;
            sum += kl * msk;
            cnt += msk;
        }
    }

    // ---- reduce: wave shuffle -> LDS -> per-block double partial ----
    #pragma unroll
    for (int off = 32; off > 0; off >>= 1) {
        sum += __shfl_down(sum, off, 64);
        cnt += __shfl_down(cnt, off, 64);
    }

    __shared__ float r_sum[BLOCK / 64];
    __shared__ float r_cnt[BLOCK / 64];
    const int wave = threadIdx.x >> 6;
    const int lane = threadIdx.x & 63;
    if (lane == 0) { r_sum[wave] = sum; r_cnt[wave] = cnt; }
    __syncthreads();

    if (threadIdx.x == 0) {
        double bs = 0.0, bc = 0.0;
        #pragma unroll
        for (int w = 0; w < BLOCK / 64; ++w) { bs += (double)r_sum[w]; bc += (double)r_cnt[w]; }
        partials[2 * blockIdx.x + 0] = bs;
        partials[2 * blockIdx.x + 1] = bc;
    }
}

__global__ __launch_bounds__(256) void isd_final_kernel(
    const double* __restrict__ partials,
    float* __restrict__ out)
{
    double s = 0.0, c = 0.0;
    for (int i = threadIdx.x; i < GRID; i += 256) {
        s += partials[2 * i + 0];
        c += partials[2 * i + 1];
    }
    #pragma unroll
    for (int off = 32; off > 0; off >>= 1) {
        s += __shfl_down(s, off, 64);
        c += __shfl_down(c, off, 64);
    }
    __shared__ double ss[4], sc[4];
    const int wave = threadIdx.x >> 6;
    const int lane = threadIdx.x & 63;
    if (lane == 0) { ss[wave] = s; sc[wave] = c; }
    __syncthreads();
    if (threadIdx.x == 0) {
        const double S  = ss[0] + ss[1] + ss[2] + ss[3];
        const double Cc = sc[0] + sc[1] + sc[2] + sc[3];
        out[0] = (Cc > 0.0) ? (float)(S / fmax(Cc, 1.0) * 0.5) : 0.0f;
    }
}

extern "C" void kernel_launch(void* const* d_in, const int* in_sizes, int n_in,
                              void* d_out, int out_size, void* d_ws, size_t ws_size,
                              hipStream_t stream) {
    const float* lam  = (const float*)d_in[0];
    const float* conf = (const float*)d_in[1];
    const float* csh  = (const float*)d_in[2];
    const float* cin  = (const float*)d_in[3];
    float* out = (float*)d_out;
    double* partials = (double*)d_ws;   // 2*GRID doubles = ~17.5 KB

    isd_main_kernel<<<GRID, BLOCK, 0, stream>>>(lam, conf, csh, cin, partials);
    isd_final_kernel<<<1, 256, 0, stream>>>(partials, out);
}

// Round 4
// 283.540 us; speedup vs baseline: 1.3201x; 1.3201x over previous
//
#include <hip/hip_runtime.h>

// ISDLoss_only_type1: masked symmetric KL between mixed conf and interpolation.
// B=128, N=8732, C=21; fp32 in, scalar fp32 out.
//
// R4: wave-autonomous LDS transpose. One wave per block, private 16.1 KB LDS
// tile, no __syncthreads. Per 64-row chunk: 21 fully-coalesced dword loads
// per tensor (256 B/inst, ~2 TA cyc vs ~64 for R1's 84 B-stride scatter),
// ds_write lane-major (2 lanes/bank = free), ds_read per-row stride-21
// (21 coprime 32 -> 2 lanes/bank = free). R3 over-fetched 3.4x (617 MB) on
// 336 B-strided float4s; R2's coalesced pattern fetched only 137 MB but its
// block barrier serialized at 2 blocks/CU. This keeps R2's fetch pattern
// with zero barriers and 10 independent waves/CU.

#define EPS 1e-7f

constexpr int B = 128;
constexpr int N = 8732;
constexpr int C = 21;
constexpr int ROWS = B * N;                    // 1,117,696
constexpr int CHUNK_ROWS = 64;
constexpr int CHUNK_ELEMS = CHUNK_ROWS * C;    // 1344 floats = 21 wave dword-loads
constexpr int CHUNKS_PER_WAVE = 8;
constexpr int GRID = ROWS / (CHUNK_ROWS * CHUNKS_PER_WAVE);  // 2183, exact
constexpr int HALF_ELEMS = (B / 2) * N * C;    // 11,735,808: batch-half swap offset

__global__ __launch_bounds__(64) void isd_main_kernel(
    const float* __restrict__ lam_p,
    const float* __restrict__ conf,
    const float* __restrict__ csh,   // conf_shuffle
    const float* __restrict__ cin,   // conf_interpolation
    double* __restrict__ partials)   // [2*GRID]: (sum, cnt) per block
{
    __shared__ float s_conf[CHUNK_ELEMS];
    __shared__ float s_csh [CHUNK_ELEMS];
    __shared__ float s_cin [CHUNK_ELEMS];

    const int lane = threadIdx.x;              // one wave per block
    const float lam = lam_p[0];
    const float oml = 1.0f - lam;

    float sum = 0.0f;
    float cnt = 0.0f;

    const int chunk0 = blockIdx.x * CHUNKS_PER_WAVE;

    for (int ci = 0; ci < CHUNKS_PER_WAVE; ++ci) {
        const int base = (chunk0 + ci) * CHUNK_ELEMS;

        // ---- stage: 63 coalesced dword loads into registers ----
        float rc[C], rs[C], ri[C];
        #pragma unroll
        for (int k = 0; k < C; ++k) {
            const int e = base + k * 64 + lane;
            rc[k] = conf[e];
            ri[k] = cin[e];
            // batch-half swap: element e is in batches [0,64) iff e < HALF_ELEMS
            const int e2 = (e < HALF_ELEMS) ? (e + HALF_ELEMS) : (e - HALF_ELEMS);
            rs[k] = csh[e2];
        }
        // ---- transpose through LDS (wave-synchronous, no barrier) ----
        #pragma unroll
        for (int k = 0; k < C; ++k) {
            s_conf[k * 64 + lane] = rc[k];
            s_csh [k * 64 + lane] = rs[k];
            s_cin [k * 64 + lane] = ri[k];
        }

        // ---- compute: one lane per row, stride-21 LDS reads ----
        const float* pc = s_conf + lane * C;
        const float* pt = s_csh  + lane * C;
        const float* pi = s_cin  + lane * C;

        float c0 = 0.0f, t0 = 0.0f;
        float cmax = -1e30f, tmax = -1e30f;
        float kl = 0.0f;

        #pragma unroll
        for (int c = 0; c < C; ++c) {
            const float cv = pc[c];
            const float tv = pt[c];
            const float iv = pi[c] + EPS;
            const float mv = fmaf(lam, cv, oml * tv) + EPS;
            // kl_a + kl_b per class: iv*(li-lm) + mv*(lm-li) == (iv-mv)*(li-lm)
            kl += (iv - mv) * (__logf(iv) - __logf(mv));
            if (c == 0) { c0 = cv; t0 = tv; }
            else        { cmax = fmaxf(cmax, cv); tmax = fmaxf(tmax, tv); }
        }

        const float msk = ((cmax > c0) && (tmax > t0)) ? 1.0f : 0.0f;
        sum += kl * msk;
        cnt += msk;
    }

    // ---- reduce: wave shuffle -> double partial per block ----
    #pragma unroll
    for (int off = 32; off > 0; off >>= 1) {
        sum += __shfl_down(sum, off, 64);
        cnt += __shfl_down(cnt, off, 64);
    }

    if (lane == 0) {
        partials[2 * blockIdx.x + 0] = (double)sum;
        partials[2 * blockIdx.x + 1] = (double)cnt;
    }
}

__global__ __launch_bounds__(256) void isd_final_kernel(
    const double* __restrict__ partials,
    float* __restrict__ out)
{
    double s = 0.0, c = 0.0;
    for (int i = threadIdx.x; i < GRID; i += 256) {
        s += partials[2 * i + 0];
        c += partials[2 * i + 1];
    }
    #pragma unroll
    for (int off = 32; off > 0; off >>= 1) {
        s += __shfl_down(s, off, 64);
        c += __shfl_down(c, off, 64);
    }
    __shared__ double ss[4], sc[4];
    const int wave = threadIdx.x >> 6;
    const int lane = threadIdx.x & 63;
    if (lane == 0) { ss[wave] = s; sc[wave] = c; }
    __syncthreads();
    if (threadIdx.x == 0) {
        const double S  = ss[0] + ss[1] + ss[2] + ss[3];
        const double Cc = sc[0] + sc[1] + sc[2] + sc[3];
        out[0] = (Cc > 0.0) ? (float)(S / fmax(Cc, 1.0) * 0.5) : 0.0f;
    }
}

extern "C" void kernel_launch(void* const* d_in, const int* in_sizes, int n_in,
                              void* d_out, int out_size, void* d_ws, size_t ws_size,
                              hipStream_t stream) {
    const float* lam  = (const float*)d_in[0];
    const float* conf = (const float*)d_in[1];
    const float* csh  = (const float*)d_in[2];
    const float* cin  = (const float*)d_in[3];
    float* out = (float*)d_out;
    double* partials = (double*)d_ws;   // 2*GRID doubles = ~35 KB

    isd_main_kernel<<<GRID, 64, 0, stream>>>(lam, conf, csh, cin, partials);
    isd_final_kernel<<<1, 256, 0, stream>>>(partials, out);
}

// Round 5
// 281.614 us; speedup vs baseline: 1.3291x; 1.0068x over previous
//
#include <hip/hip_runtime.h>

// ISDLoss_only_type1: masked symmetric KL between mixed conf and interpolation.
// B=128, N=8732, C=21; fp32 in, scalar fp32 out.
//
// R5: R4's wave-autonomous LDS transpose (coalesced dword staging, no
// barriers, conflict-free LDS) + register double-buffer PREFETCH of the next
// chunk, issued before the current chunk's compute, so the ~900-cyc HBM
// latency overlaps ~1500 cyc of LDS+log work. R4 was latency-bound: 2183
// waves (~2/SIMD) each running a serial load->vmcnt(0)->write->read->compute
// chain (126 us, 18% VALUBusy, 1.1 TB/s, FETCH already minimal at 137 MB).
// Also 2x blocks (4 chunks/wave -> 4366 blocks) for residency and balance.

#define EPS 1e-7f

constexpr int B = 128;
constexpr int N = 8732;
constexpr int C = 21;
constexpr int ROWS = B * N;                    // 1,117,696
constexpr int CHUNK_ROWS = 64;
constexpr int CHUNK_ELEMS = CHUNK_ROWS * C;    // 1344 floats = 21 wave dword-loads
constexpr int CPW = 4;                         // chunks per wave
constexpr int GRID = ROWS / (CHUNK_ROWS * CPW);  // 4366, exact
constexpr int HALF_ELEMS = (B / 2) * N * C;    // 11,735,808: batch-half swap offset

__device__ __forceinline__ void stage_load(
    const float* __restrict__ conf,
    const float* __restrict__ csh,
    const float* __restrict__ cin,
    int base, int lane,
    float* rc, float* rs, float* ri)
{
    #pragma unroll
    for (int k = 0; k < C; ++k) {
        const int e = base + k * 64 + lane;
        rc[k] = conf[e];
        ri[k] = cin[e];
        // batch-half swap: element e is in batches [0,64) iff e < HALF_ELEMS
        const int e2 = (e < HALF_ELEMS) ? (e + HALF_ELEMS) : (e - HALF_ELEMS);
        rs[k] = csh[e2];
    }
}

__global__ __launch_bounds__(64) void isd_main_kernel(
    const float* __restrict__ lam_p,
    const float* __restrict__ conf,
    const float* __restrict__ csh,   // conf_shuffle
    const float* __restrict__ cin,   // conf_interpolation
    double* __restrict__ partials)   // [2*GRID]: (sum, cnt) per block
{
    __shared__ float s_conf[CHUNK_ELEMS];
    __shared__ float s_csh [CHUNK_ELEMS];
    __shared__ float s_cin [CHUNK_ELEMS];

    const int lane = threadIdx.x;              // one wave per block
    const float lam = lam_p[0];
    const float oml = 1.0f - lam;

    float sum = 0.0f;
    float cnt = 0.0f;

    const int chunk0 = blockIdx.x * CPW;

    float A0[C], A1[C], A2[C];   // current chunk (register-staged)
    float B0[C], B1[C], B2[C];   // prefetch buffer

    stage_load(conf, csh, cin, chunk0 * CHUNK_ELEMS, lane, A0, A1, A2);

    #pragma unroll
    for (int ci = 0; ci < CPW; ++ci) {
        // ---- prefetch next chunk's registers (loads stay in flight over compute) ----
        if (ci + 1 < CPW)
            stage_load(conf, csh, cin, (chunk0 + ci + 1) * CHUNK_ELEMS, lane, B0, B1, B2);

        // ---- transpose current chunk through LDS (wave-synchronous, no barrier) ----
        #pragma unroll
        for (int k = 0; k < C; ++k) {
            s_conf[k * 64 + lane] = A0[k];
            s_csh [k * 64 + lane] = A1[k];
            s_cin [k * 64 + lane] = A2[k];
        }

        // ---- compute: one lane per row, stride-21 LDS reads (2 lanes/bank = free) ----
        const float* pc = s_conf + lane * C;
        const float* pt = s_csh  + lane * C;
        const float* pi = s_cin  + lane * C;

        float c0 = 0.0f, t0 = 0.0f;
        float cmax = -1e30f, tmax = -1e30f;
        float kl = 0.0f;

        #pragma unroll
        for (int c = 0; c < C; ++c) {
            const float cv = pc[c];
            const float tv = pt[c];
            const float iv = pi[c] + EPS;
            const float mv = fmaf(lam, cv, oml * tv) + EPS;
            // kl_a + kl_b per class: iv*(li-lm) + mv*(lm-li) == (iv-mv)*(li-lm)
            kl += (iv - mv) * (__logf(iv) - __logf(mv));
            if (c == 0) { c0 = cv; t0 = tv; }
            else        { cmax = fmaxf(cmax, cv); tmax = fmaxf(tmax, tv); }
        }

        const float msk = ((cmax > c0) && (tmax > t0)) ? 1.0f : 0.0f;
        sum += kl * msk;
        cnt += msk;

        // ---- rotate buffers (pure renames after full unroll) ----
        if (ci + 1 < CPW) {
            #pragma unroll
            for (int k = 0; k < C; ++k) { A0[k] = B0[k]; A1[k] = B1[k]; A2[k] = B2[k]; }
        }
    }

    // ---- reduce: wave shuffle -> double partial per block ----
    #pragma unroll
    for (int off = 32; off > 0; off >>= 1) {
        sum += __shfl_down(sum, off, 64);
        cnt += __shfl_down(cnt, off, 64);
    }

    if (lane == 0) {
        partials[2 * blockIdx.x + 0] = (double)sum;
        partials[2 * blockIdx.x + 1] = (double)cnt;
    }
}

__global__ __launch_bounds__(256) void isd_final_kernel(
    const double* __restrict__ partials,
    float* __restrict__ out)
{
    double s = 0.0, c = 0.0;
    for (int i = threadIdx.x; i < GRID; i += 256) {
        s += partials[2 * i + 0];
        c += partials[2 * i + 1];
    }
    #pragma unroll
    for (int off = 32; off > 0; off >>= 1) {
        s += __shfl_down(s, off, 64);
        c += __shfl_down(c, off, 64);
    }
    __shared__ double ss[4], sc[4];
    const int wave = threadIdx.x >> 6;
    const int lane = threadIdx.x & 63;
    if (lane == 0) { ss[wave] = s; sc[wave] = c; }
    __syncthreads();
    if (threadIdx.x == 0) {
        const double S  = ss[0] + ss[1] + ss[2] + ss[3];
        const double Cc = sc[0] + sc[1] + sc[2] + sc[3];
        out[0] = (Cc > 0.0) ? (float)(S / fmax(Cc, 1.0) * 0.5) : 0.0f;
    }
}

extern "C" void kernel_launch(void* const* d_in, const int* in_sizes, int n_in,
                              void* d_out, int out_size, void* d_ws, size_t ws_size,
                              hipStream_t stream) {
    const float* lam  = (const float*)d_in[0];
    const float* conf = (const float*)d_in[1];
    const float* csh  = (const float*)d_in[2];
    const float* cin  = (const float*)d_in[3];
    float* out = (float*)d_out;
    double* partials = (double*)d_ws;   // 2*GRID doubles = ~70 KB

    isd_main_kernel<<<GRID, 64, 0, stream>>>(lam, conf, csh, cin, partials);
    isd_final_kernel<<<1, 256, 0, stream>>>(partials, out);
}